// Round 8
// baseline (238.937 us; speedup 1.0000x reference)
//
#include <hip/hip_runtime.h>

typedef _Float16 half8 __attribute__((ext_vector_type(8)));
typedef float floatx4 __attribute__((ext_vector_type(4)));
typedef int intx4 __attribute__((ext_vector_type(4)));

#define MFMA16(a, b, c) __builtin_amdgcn_mfma_f32_16x16x32_f16(a, b, c, 0, 0, 0)

static constexpr int kD = 576;
// ws layout (f16 elements):
//   WS1 (GEMM1 B, hi/lo interleaved per k-octet): [m:512][k8:72][16] -> 2304 B/row
//   WS2 (GEMM2 B, hi only): [d:576][m:512] -> 1024 B/row
static constexpr int WS2 = 589824;
// total ws: 884736 f16 = 1,769,472 bytes

__global__ void prep_split(const float* __restrict__ mem, _Float16* __restrict__ ws) {
  const int m = blockIdx.x;   // 512
  const int d = threadIdx.x;  // 576
  float v = mem[m * kD + d];
  _Float16 hi = (_Float16)v;
  _Float16 lo = (_Float16)(v - (float)hi);
  ws[m * 1152 + ((d >> 3) << 4) + (d & 7)] = hi;
  ws[m * 1152 + ((d >> 3) << 4) + (d & 7) + 8] = lo;
  ws[WS2 + d * 512 + m] = hi;
}

#define GLD_LDS16(gp, lp)                                                          \
  __builtin_amdgcn_global_load_lds((__attribute__((address_space(1))) void*)(gp),  \
                                   (__attribute__((address_space(3))) void*)(lp),  \
                                   16, 0, 0)
#define SBAR asm volatile("s_barrier" ::: "memory")
#define VMW(N)                                            \
  do {                                                    \
    asm volatile("s_waitcnt vmcnt(" #N ")" ::: "memory"); \
    __builtin_amdgcn_sched_barrier(0);                    \
  } while (0)

// One block: 64 pixels = one (b,h) row. 512 threads / 8 waves. 1 block/CU.
__global__ __launch_bounds__(512, 2) void mem_branch_kernel(
    const float* __restrict__ x, const float* __restrict__ temperature,
    const _Float16* __restrict__ ws, float* __restrict__ out) {
  // A-frags: [72 combos (kt*4+pt)][64 lanes][8 f16] = 73,728 B.
  // Reused for att-frags: [64 combos (kt2*4+pt)][64][8] = 65,536 B.
  __shared__ __align__(16) _Float16 afrag[36864];
  __shared__ __align__(16) unsigned char stg[73728];  // double-buffered B staging
  __shared__ float redm[512];
  __shared__ float reds[512];
  __shared__ __align__(16) int tab[kD];

  const int tid = threadIdx.x;
  const int lane = tid & 63;
  const int wv = tid >> 6;  // 0..7
  const int l15 = lane & 15;
  const int koct = lane >> 4;  // 0..3
  const int bx = blockIdx.x;   // 1024
  const int b = bx >> 6;
  const int h = bx & 63;
  const int s1 = ((bx >> 3) * 7) % 18;  // G1 kt rotation (decorrelate L2 camping)
  const int s2 = ((bx >> 3) * 5) & 15;  // G2 kt2 rotation

  const float sfac = temperature[0] * 0.060112293370373475f;  // (1/24)*log2(e)
  const unsigned char* wsb = (const unsigned char*)ws;

  for (int d = tid; d < kD; d += 512) {
    int c = d / 9, r9 = d % 9, kh = r9 / 3, kw = r9 % 3;
    tab[d] = (c << 12) + (kh << 6) + kw + (kh << 20) + (kw << 24);
  }
  __syncthreads();

  // ---- build A-hi fragments (64 px = full w row) in fragment layout ----
  {
    const int base0 = (b * 4096 + (h - 1)) * 64 - 1;
    for (int i = 0; i < 9; ++i) {
      const int combo = i * 8 + wv;  // 0..71 = kt*4 + pt
      const int pt = combo & 3;
      const int kt = combo >> 2;
      const int pp = pt * 16 + l15;  // px = w
      const int dbase = kt * 32 + koct * 8;
      intx4 t0 = *reinterpret_cast<const intx4*>(&tab[dbase]);
      intx4 t1 = *reinterpret_cast<const intx4*>(&tab[dbase + 4]);
      half8 hv;
#pragma unroll
      for (int j = 0; j < 8; ++j) {
        int t = (j < 4) ? t0[j] : t1[j - 4];
        int off = t & 0xFFFFF;
        int kh = (t >> 20) & 15;
        int kw = (t >> 24) & 15;
        bool ok = ((unsigned)(h - 1 + kh) < 64u) && ((unsigned)(pp - 1 + kw) < 64u);
        int idx = ok ? (base0 + pp + off) : 0;
        float v = x[idx];
        v = ok ? v : 0.0f;
        hv[j] = (_Float16)v;
      }
      *reinterpret_cast<half8*>(&afrag[combo * 512 + lane * 8]) = hv;
    }
  }
  __syncthreads();  // A-frags visible to all waves

  // ---- GEMM1 (2-term hi*(hi+lo)): wave owns m-range [wv*64, +64), all 64 px ----
  // Pieces p=0..35: kt=((p>>1)+s1)%18, half=p&1 (0=hi,1=lo). 32KB/piece, dbuf.
  floatx4 acc[4][4];  // [pt][mt]
  const floatx4 zed = {0.0f, 0.0f, 0.0f, 0.0f};
#pragma unroll
  for (int pt = 0; pt < 4; ++pt)
#pragma unroll
    for (int mt = 0; mt < 4; ++mt) acc[pt][mt] = zed;
  {
    // pre-swizzled source bases: LDS piece row m = 64B, inner ^= (m&3)<<4
    int sb1[4];
#pragma unroll
    for (int ch = 0; ch < 4; ++ch) {
      const int o = (wv * 4 + ch) * 1024 + lane * 16;
      const int m = o >> 6;
      const int q0 = (o >> 4) & 3;
      sb1[ch] = m * 2304 + ((q0 ^ (m & 3)) << 5);
    }

#define G1_STAGE(PK, HH, BUF)                                                   \
  do {                                                                          \
    const int off_ = (PK)*128 + (HH)*16;                                        \
    _Pragma("unroll") for (int ch = 0; ch < 4; ++ch)                            \
        GLD_LDS16(wsb + (sb1[ch] + off_), stg + (BUF) + (wv * 4 + ch) * 1024);  \
  } while (0)

#define G1_MFMA(BUF)                                                            \
  do {                                                                          \
    _Pragma("unroll") for (int mt = 0; mt < 4; ++mt) {                          \
      const int mr = wv * 64 + mt * 16 + l15;                                   \
      const half8 bb = *reinterpret_cast<const half8*>(                         \
          stg + (BUF) + mr * 64 + ((koct * 16) ^ ((mr & 3) << 4)));             \
      __builtin_amdgcn_s_setprio(1);                                            \
      acc[0][mt] = MFMA16(aa0, bb, acc[0][mt]);                                 \
      acc[1][mt] = MFMA16(aa1, bb, acc[1][mt]);                                 \
      acc[2][mt] = MFMA16(aa2, bb, acc[2][mt]);                                 \
      acc[3][mt] = MFMA16(aa3, bb, acc[3][mt]);                                 \
      __builtin_amdgcn_s_setprio(0);                                            \
    }                                                                           \
  } while (0)

    G1_STAGE(s1, 0, 0);  // prologue: piece 0 -> buf0
    for (int p = 0; p < 35; ++p) {
      SBAR;  // all waves done with MFMA(p-1) -> buf[(p+1)&1] free
      const int pn = p + 1;
      const int pkn = ((pn >> 1) + s1) % 18;
      G1_STAGE(pkn, pn & 1, (pn & 1) * 32768);
      const int pk = ((p >> 1) + s1) % 18;
      half8 aa0 = *reinterpret_cast<const half8*>(&afrag[(pk * 4 + 0) * 512 + lane * 8]);
      half8 aa1 = *reinterpret_cast<const half8*>(&afrag[(pk * 4 + 1) * 512 + lane * 8]);
      half8 aa2 = *reinterpret_cast<const half8*>(&afrag[(pk * 4 + 2) * 512 + lane * 8]);
      half8 aa3 = *reinterpret_cast<const half8*>(&afrag[(pk * 4 + 3) * 512 + lane * 8]);
      VMW(4);  // own piece-p loads complete (4 of p+1 outstanding)
      SBAR;    // everyone's piece-p loads complete
      G1_MFMA((p & 1) * 32768);
    }
    // tail p = 35
    SBAR;
    {
      const int pk = (17 + s1) % 18;
      half8 aa0 = *reinterpret_cast<const half8*>(&afrag[(pk * 4 + 0) * 512 + lane * 8]);
      half8 aa1 = *reinterpret_cast<const half8*>(&afrag[(pk * 4 + 1) * 512 + lane * 8]);
      half8 aa2 = *reinterpret_cast<const half8*>(&afrag[(pk * 4 + 2) * 512 + lane * 8]);
      half8 aa3 = *reinterpret_cast<const half8*>(&afrag[(pk * 4 + 3) * 512 + lane * 8]);
      VMW(0);
      SBAR;
      G1_MFMA(32768);
    }
  }

  // ---- softmax over m=512; lane holds px = pt*16+koct*4+r, m = wv*64+mt*16+l15 ----
  float pm[4][4], ps[4][4];
#pragma unroll
  for (int pt = 0; pt < 4; ++pt)
#pragma unroll
    for (int r = 0; r < 4; ++r) {
      float v = acc[pt][0][r];
#pragma unroll
      for (int mt = 1; mt < 4; ++mt) v = fmaxf(v, acc[pt][mt][r]);
      pm[pt][r] = v;
    }
#pragma unroll
  for (int off = 1; off < 16; off <<= 1)
#pragma unroll
    for (int pt = 0; pt < 4; ++pt)
#pragma unroll
      for (int r = 0; r < 4; ++r) pm[pt][r] = fmaxf(pm[pt][r], __shfl_xor(pm[pt][r], off, 64));
  if (l15 == 0) {
#pragma unroll
    for (int pt = 0; pt < 4; ++pt)
#pragma unroll
      for (int r = 0; r < 4; ++r) redm[wv * 64 + pt * 16 + koct * 4 + r] = pm[pt][r];
  }
  __syncthreads();
#pragma unroll
  for (int pt = 0; pt < 4; ++pt)
#pragma unroll
    for (int r = 0; r < 4; ++r) {
      const int p = pt * 16 + koct * 4 + r;
      float g = redm[p];
#pragma unroll
      for (int w = 1; w < 8; ++w) g = fmaxf(g, redm[w * 64 + p]);
      pm[pt][r] = g;
      ps[pt][r] = 0.0f;
    }
#pragma unroll
  for (int pt = 0; pt < 4; ++pt)
#pragma unroll
    for (int mt = 0; mt < 4; ++mt)
#pragma unroll
      for (int r = 0; r < 4; ++r) {
        float e = exp2f((acc[pt][mt][r] - pm[pt][r]) * sfac);
        acc[pt][mt][r] = e;
        ps[pt][r] += e;
      }
#pragma unroll
  for (int off = 1; off < 16; off <<= 1)
#pragma unroll
    for (int pt = 0; pt < 4; ++pt)
#pragma unroll
      for (int r = 0; r < 4; ++r) ps[pt][r] += __shfl_xor(ps[pt][r], off, 64);
  if (l15 == 0) {
#pragma unroll
    for (int pt = 0; pt < 4; ++pt)
#pragma unroll
      for (int r = 0; r < 4; ++r) reds[wv * 64 + pt * 16 + koct * 4 + r] = ps[pt][r];
  }
  __syncthreads();
#pragma unroll
  for (int pt = 0; pt < 4; ++pt)
#pragma unroll
    for (int r = 0; r < 4; ++r) {
      const int p = pt * 16 + koct * 4 + r;
      float s = reds[p];
#pragma unroll
      for (int w = 1; w < 8; ++w) s += reds[w * 64 + p];
      ps[pt][r] = 1.0f / s;
    }
  // write att-hi fragments into (aliased) afrag: [kt2*4+pt][lane'][j']
#pragma unroll
  for (int pt = 0; pt < 4; ++pt)
#pragma unroll
    for (int mt = 0; mt < 4; ++mt)
#pragma unroll
      for (int r = 0; r < 4; ++r) {
        float a = acc[pt][mt][r] * ps[pt][r];
        const int m = wv * 64 + mt * 16 + l15;
        const int idxe = (((m >> 5) * 4 + pt) * 64 + ((m >> 3) & 3) * 16 + koct * 4 + r) * 8 + (m & 7);
        afrag[idxe] = (_Float16)a;
      }
  __syncthreads();  // att-frags visible; stage region free

  // ---- GEMM2 (hi-only): out[64][576] = att_hi @ mem_hi. Pieces = full kt2 (36KB), dbuf ----
  floatx4 acc2[5][4];  // [nt][pt]
#pragma unroll
  for (int nt = 0; nt < 5; ++nt)
#pragma unroll
    for (int pt = 0; pt < 4; ++pt) acc2[nt][pt] = zed;
  {
    int sb2[5];
    int dst2[5];
#pragma unroll
    for (int ch = 0; ch < 5; ++ch) {
      const int q = (ch < 4) ? (ch * 8 + wv) : (32 + wv);
      if (q < 36) {
        const int o = q * 1024 + lane * 16;
        const int dd = o >> 6;
        const int inner = o & 63;
        sb2[ch] = WS2 * 2 + dd * 1024 + (inner ^ ((dd & 3) << 4));
        dst2[ch] = q * 1024;
      } else {
        sb2[ch] = 0;
        dst2[ch] = -1;
      }
    }

#define G2_STAGE(KT2, BUF)                                                       \
  do {                                                                           \
    const int off_ = (KT2)*64;                                                   \
    _Pragma("unroll") for (int ch = 0; ch < 5; ++ch) {                           \
      if (ch < 4 || wv < 4) GLD_LDS16(wsb + (sb2[ch] + off_), stg + (BUF) + dst2[ch]); \
    }                                                                            \
  } while (0)

#define G2_MFMA(BUF)                                                             \
  do {                                                                           \
    _Pragma("unroll") for (int nt = 0; nt < 5; ++nt) {                           \
      if (nt < 4 || wv < 4) {                                                    \
        const int dtile = (nt < 4) ? (wv * 4 + nt) : (32 + wv);                  \
        const int row = dtile * 16 + l15;                                        \
        const half8 bb = *reinterpret_cast<const half8*>(                        \
            stg + (BUF) + row * 64 + ((koct * 16) ^ ((row & 3) << 4)));          \
        __builtin_amdgcn_s_setprio(1);                                           \
        acc2[nt][0] = MFMA16(p0, bb, acc2[nt][0]);                               \
        acc2[nt][1] = MFMA16(p1, bb, acc2[nt][1]);                               \
        acc2[nt][2] = MFMA16(p2, bb, acc2[nt][2]);                               \
        acc2[nt][3] = MFMA16(p3, bb, acc2[nt][3]);                               \
        __builtin_amdgcn_s_setprio(0);                                           \
      }                                                                          \
    }                                                                            \
  } while (0)

    G2_STAGE(s2, 0);  // prologue: piece 0 -> buf0
    for (int P = 0; P < 15; ++P) {
      SBAR;
      const int ktn = (P + 1 + s2) & 15;
      G2_STAGE(ktn, ((P + 1) & 1) * 36864);
      const int kt2 = (P + s2) & 15;
      half8 p0 = *reinterpret_cast<const half8*>(&afrag[((kt2 * 4 + 0) * 64 + lane) * 8]);
      half8 p1 = *reinterpret_cast<const half8*>(&afrag[((kt2 * 4 + 1) * 64 + lane) * 8]);
      half8 p2 = *reinterpret_cast<const half8*>(&afrag[((kt2 * 4 + 2) * 64 + lane) * 8]);
      half8 p3 = *reinterpret_cast<const half8*>(&afrag[((kt2 * 4 + 3) * 64 + lane) * 8]);
      if (wv < 4) {
        VMW(5);
      } else {
        VMW(4);
      }
      SBAR;
      G2_MFMA((P & 1) * 36864);
    }
    // tail P = 15
    SBAR;
    {
      const int kt2 = (15 + s2) & 15;
      half8 p0 = *reinterpret_cast<const half8*>(&afrag[((kt2 * 4 + 0) * 64 + lane) * 8]);
      half8 p1 = *reinterpret_cast<const half8*>(&afrag[((kt2 * 4 + 1) * 64 + lane) * 8]);
      half8 p2 = *reinterpret_cast<const half8*>(&afrag[((kt2 * 4 + 2) * 64 + lane) * 8]);
      half8 p3 = *reinterpret_cast<const half8*>(&afrag[((kt2 * 4 + 3) * 64 + lane) * 8]);
      VMW(0);
      SBAR;
      G2_MFMA(36864);
    }
  }

  // ---- epilogue: nontemporal stores ----
  {
    const int nbase = b * 4096 + h * 64;
#pragma unroll
    for (int nt = 0; nt < 5; ++nt) {
      if (nt < 4 || wv < 4) {
        const int dtile = (nt < 4) ? (wv * 4 + nt) : (32 + wv);
        const int d = dtile * 16 + l15;
#pragma unroll
        for (int pt = 0; pt < 4; ++pt)
#pragma unroll
          for (int r = 0; r < 4; ++r) {
            const int px = pt * 16 + koct * 4 + r;
            __builtin_nontemporal_store(acc2[nt][pt][r], &out[(nbase + px) * 576 + d]);
          }
      }
    }
  }
}

extern "C" void kernel_launch(void* const* d_in, const int* in_sizes, int n_in,
                              void* d_out, int out_size, void* d_ws, size_t ws_size,
                              hipStream_t stream) {
  const float* x = (const float*)d_in[0];
  const float* memory = (const float*)d_in[1];
  const float* temperature = (const float*)d_in[2];
  float* out = (float*)d_out;
  _Float16* ws = (_Float16*)d_ws;  // needs 1,769,472 bytes

  prep_split<<<512, 576, 0, stream>>>(memory, ws);
  mem_branch_kernel<<<1024, 512, 0, stream>>>(x, temperature, ws, out);
}

// Round 9
// 189.298 us; speedup vs baseline: 1.2622x; 1.2622x over previous
//
#include <hip/hip_runtime.h>

typedef _Float16 half8 __attribute__((ext_vector_type(8)));
typedef float floatx4 __attribute__((ext_vector_type(4)));
typedef int intx4 __attribute__((ext_vector_type(4)));

#define MFMA16(a, b, c) __builtin_amdgcn_mfma_f32_16x16x32_f16(a, b, c, 0, 0, 0)

static constexpr int kD = 576;
// ws layout (f16 elements):
//   WS1 (GEMM1 B): [m:512] rows of 1152 f16 (2304B): per kt (18): [hi 32 f16 | lo 32 f16]
//        hi elem = m*1152 + kt*64 + koct*8 + j ; lo = +32   (planar 64B halves)
//   WS2 (GEMM2 B, hi only): [d:576][m:512] -> 1024 B/row
static constexpr int WS2 = 589824;
// total ws: 884736 f16 = 1,769,472 bytes

__global__ void prep_split(const float* __restrict__ mem, _Float16* __restrict__ ws) {
  const int m = blockIdx.x;   // 512
  const int d = threadIdx.x;  // 576
  float v = mem[m * kD + d];
  _Float16 hi = (_Float16)v;
  _Float16 lo = (_Float16)(v - (float)hi);
  const int kt = d >> 5, koct = (d >> 3) & 3, j = d & 7;
  ws[m * 1152 + kt * 64 + koct * 8 + j] = hi;
  ws[m * 1152 + kt * 64 + koct * 8 + j + 32] = lo;
  ws[WS2 + d * 512 + m] = hi;
}

#define GLD_LDS16(gp, lp)                                                          \
  __builtin_amdgcn_global_load_lds((__attribute__((address_space(1))) void*)(gp),  \
                                   (__attribute__((address_space(3))) void*)(lp),  \
                                   16, 0, 0)
#define VMW(N)                                            \
  do {                                                    \
    asm volatile("s_waitcnt vmcnt(" #N ")" ::: "memory"); \
    __builtin_amdgcn_sched_barrier(0);                    \
  } while (0)

// One block: 64 pixels = one (b,h) row. 512 threads / 8 waves. 1 block/CU.
// Wave-decoupled: staged B is partitioned per wave -> private LDS rings,
// per-wave counted vmcnt, NO barriers inside either GEMM loop.
__global__ __launch_bounds__(512, 2) void mem_branch_kernel(
    const float* __restrict__ x, const float* __restrict__ temperature,
    const _Float16* __restrict__ ws, float* __restrict__ out) {
  // blob layout (159744 B):
  //  [0,73728)        A-frags (G1) -> att-frags (G2, 65536 used)
  //  [73728,155648)   private stage rings (G1: 8x8KB; G2: 8x10KB); tab aliased pre-G1
  //  [155648,157696)  redm[512]   [157696,159744) reds[512]
  __shared__ __align__(16) unsigned char blob[159744];
  _Float16* afrag = (_Float16*)blob;
  int* tab = (int*)(blob + 73728);
  float* redm = (float*)(blob + 155648);
  float* reds = (float*)(blob + 157696);

  const int tid = threadIdx.x;
  const int lane = tid & 63;
  const int wv = tid >> 6;  // 0..7
  const int l15 = lane & 15;
  const int koct = lane >> 4;  // 0..3
  const int bx = blockIdx.x;   // 1024
  const int b = bx >> 6;
  const int h = bx & 63;

  const float sfac = temperature[0] * 0.060112293370373475f;  // (1/24)*log2(e)
  const unsigned char* wsb = (const unsigned char*)ws;

  for (int d = tid; d < kD; d += 512) {
    int c = d / 9, r9 = d % 9, kh = r9 / 3, kw = r9 % 3;
    tab[d] = (c << 12) + (kh << 6) + kw + (kh << 20) + (kw << 24);
  }
  __syncthreads();

  // ---- build A-hi fragments (64 px = full w row) in fragment layout ----
  {
    const int base0 = (b * 4096 + (h - 1)) * 64 - 1;
    for (int i = 0; i < 9; ++i) {
      const int combo = i * 8 + wv;  // 0..71 = kt*4 + pt
      const int pt = combo & 3;
      const int kt = combo >> 2;
      const int pp = pt * 16 + l15;  // px = w
      const int dbase = kt * 32 + koct * 8;
      intx4 t0 = *reinterpret_cast<const intx4*>(&tab[dbase]);
      intx4 t1 = *reinterpret_cast<const intx4*>(&tab[dbase + 4]);
      half8 hv;
#pragma unroll
      for (int j = 0; j < 8; ++j) {
        int t = (j < 4) ? t0[j] : t1[j - 4];
        int off = t & 0xFFFFF;
        int kh = (t >> 20) & 15;
        int kw = (t >> 24) & 15;
        bool ok = ((unsigned)(h - 1 + kh) < 64u) && ((unsigned)(pp - 1 + kw) < 64u);
        int idx = ok ? (base0 + pp + off) : 0;
        float v = x[idx];
        v = ok ? v : 0.0f;
        hv[j] = (_Float16)v;
      }
      *reinterpret_cast<half8*>(&afrag[combo * 512 + lane * 8]) = hv;
    }
  }
  __syncthreads();  // A-frags visible; tab dead -> rings region free

  // ---- GEMM1 (2-term hi*(hi+lo)): wave owns m in [wv*64,+64), all 64 px ----
  // 36 sub-pieces p: kt=p>>1, half=p&1 (0=hi,1=lo). Private ring 2 x 4KB.
  floatx4 acc[4][4];  // [pt][mt]
  const floatx4 zed = {0.0f, 0.0f, 0.0f, 0.0f};
#pragma unroll
  for (int pt = 0; pt < 4; ++pt)
#pragma unroll
    for (int mt = 0; mt < 4; ++mt) acc[pt][mt] = zed;
  {
    // stage src base per ch: dest local (4KB): r = ch*16 + lane>>2 (64B rows),
    // slot s = lane&3; stored chunk = s ^ ((r>>1)&3)  (read applies same XOR)
    int sb1[4];
#pragma unroll
    for (int ch = 0; ch < 4; ++ch) {
      const int r = ch * 16 + (lane >> 2);
      const int m = wv * 64 + r;
      sb1[ch] = m * 2304 + (((lane & 3) ^ ((r >> 1) & 3)) << 4);
    }
    unsigned char* ring1 = blob + 73728 + wv * 8192;

    auto g1_stage = [&](int p) {
      const int off = (p >> 1) * 128 + (p & 1) * 64;
      unsigned char* dst = ring1 + (p & 1) * 4096;
#pragma unroll
      for (int ch = 0; ch < 4; ++ch) GLD_LDS16(wsb + (sb1[ch] + off), dst + ch * 1024);
    };

    half8 aa0, aa1, aa2, aa3;
    auto g1_mma = [&](int p) {
      const unsigned char* bufb = ring1 + (p & 1) * 4096;
      __builtin_amdgcn_s_setprio(1);
#pragma unroll
      for (int mt = 0; mt < 4; ++mt) {
        const int r = mt * 16 + l15;
        const half8 bb = *reinterpret_cast<const half8*>(
            bufb + r * 64 + ((koct ^ ((r >> 1) & 3)) << 4));
        acc[0][mt] = MFMA16(aa0, bb, acc[0][mt]);
        acc[1][mt] = MFMA16(aa1, bb, acc[1][mt]);
        acc[2][mt] = MFMA16(aa2, bb, acc[2][mt]);
        acc[3][mt] = MFMA16(aa3, bb, acc[3][mt]);
      }
      __builtin_amdgcn_s_setprio(0);
    };

    g1_stage(0);
    for (int p = 0; p < 35; ++p) {
      g1_stage(p + 1);
      if ((p & 1) == 0) {
        const int kt = p >> 1;
        aa0 = *reinterpret_cast<const half8*>(&afrag[(kt * 4 + 0) * 512 + lane * 8]);
        aa1 = *reinterpret_cast<const half8*>(&afrag[(kt * 4 + 1) * 512 + lane * 8]);
        aa2 = *reinterpret_cast<const half8*>(&afrag[(kt * 4 + 2) * 512 + lane * 8]);
        aa3 = *reinterpret_cast<const half8*>(&afrag[(kt * 4 + 3) * 512 + lane * 8]);
      }
      VMW(4);  // own sub-piece p complete (4 of p+1 outstanding)
      g1_mma(p);
    }
    VMW(0);
    g1_mma(35);
  }

  // ---- softmax over m=512; lane: px = pt*16+koct*4+r, m = wv*64+mt*16+l15 ----
  float pm[4][4], ps[4][4];
#pragma unroll
  for (int pt = 0; pt < 4; ++pt)
#pragma unroll
    for (int r = 0; r < 4; ++r) {
      float v = acc[pt][0][r];
#pragma unroll
      for (int mt = 1; mt < 4; ++mt) v = fmaxf(v, acc[pt][mt][r]);
      pm[pt][r] = v;
    }
#pragma unroll
  for (int off = 1; off < 16; off <<= 1)
#pragma unroll
    for (int pt = 0; pt < 4; ++pt)
#pragma unroll
      for (int r = 0; r < 4; ++r) pm[pt][r] = fmaxf(pm[pt][r], __shfl_xor(pm[pt][r], off, 64));
  if (l15 == 0) {
#pragma unroll
    for (int pt = 0; pt < 4; ++pt)
#pragma unroll
      for (int r = 0; r < 4; ++r) redm[wv * 64 + pt * 16 + koct * 4 + r] = pm[pt][r];
  }
  __syncthreads();  // also: all waves past G1 -> A-frags/G1 rings dead
#pragma unroll
  for (int pt = 0; pt < 4; ++pt)
#pragma unroll
    for (int r = 0; r < 4; ++r) {
      const int p = pt * 16 + koct * 4 + r;
      float g = redm[p];
#pragma unroll
      for (int w = 1; w < 8; ++w) g = fmaxf(g, redm[w * 64 + p]);
      pm[pt][r] = g;
      ps[pt][r] = 0.0f;
    }
#pragma unroll
  for (int pt = 0; pt < 4; ++pt)
#pragma unroll
    for (int mt = 0; mt < 4; ++mt)
#pragma unroll
      for (int r = 0; r < 4; ++r) {
        float e = exp2f((acc[pt][mt][r] - pm[pt][r]) * sfac);
        acc[pt][mt][r] = e;
        ps[pt][r] += e;
      }
#pragma unroll
  for (int off = 1; off < 16; off <<= 1)
#pragma unroll
    for (int pt = 0; pt < 4; ++pt)
#pragma unroll
      for (int r = 0; r < 4; ++r) ps[pt][r] += __shfl_xor(ps[pt][r], off, 64);
  if (l15 == 0) {
#pragma unroll
    for (int pt = 0; pt < 4; ++pt)
#pragma unroll
      for (int r = 0; r < 4; ++r) reds[wv * 64 + pt * 16 + koct * 4 + r] = ps[pt][r];
  }
  __syncthreads();
#pragma unroll
  for (int pt = 0; pt < 4; ++pt)
#pragma unroll
    for (int r = 0; r < 4; ++r) {
      const int p = pt * 16 + koct * 4 + r;
      float s = reds[p];
#pragma unroll
      for (int w = 1; w < 8; ++w) s += reds[w * 64 + p];
      ps[pt][r] = 1.0f / s;
    }
  // write att-hi fragments into afrag region (A-frags dead since first sync)
#pragma unroll
  for (int pt = 0; pt < 4; ++pt)
#pragma unroll
    for (int mt = 0; mt < 4; ++mt)
#pragma unroll
      for (int r = 0; r < 4; ++r) {
        float a = acc[pt][mt][r] * ps[pt][r];
        const int m = wv * 64 + mt * 16 + l15;
        const int idxe =
            (((m >> 5) * 4 + pt) * 64 + ((m >> 3) & 3) * 16 + koct * 4 + r) * 8 + (m & 7);
        afrag[idxe] = (_Float16)a;
      }
  __syncthreads();  // att-frags visible to all; G1 rings dead -> G2 rings free

  // ---- GEMM2 (hi-only): out[64][576] = att_hi @ mem_hi ----
  // wave owns 5 dtiles wv*5..wv*5+4 (tiles >=36 are pad: clamped src, stores skipped)
  floatx4 acc2[5][4];  // [nt][pt]
#pragma unroll
  for (int nt = 0; nt < 5; ++nt)
#pragma unroll
    for (int pt = 0; pt < 4; ++pt) acc2[nt][pt] = zed;
  {
    int sb2[5];
#pragma unroll
    for (int ch = 0; ch < 5; ++ch) {
      const int r = ch * 16 + (lane >> 2);
      int d = wv * 80 + r;
      if (d >= 576) d -= 576;  // pad rows -> clamp to valid data (discarded later)
      sb2[ch] = WS2 * 2 + d * 1024 + (((lane & 3) ^ ((r >> 1) & 3)) << 4);
    }
    unsigned char* ring2 = blob + 73728 + wv * 10240;

    auto g2_stage = [&](int k) {
      const int off = k * 64;
      unsigned char* dst = ring2 + (k & 1) * 5120;
#pragma unroll
      for (int ch = 0; ch < 5; ++ch) GLD_LDS16(wsb + (sb2[ch] + off), dst + ch * 1024);
    };

    half8 p0, p1, p2, p3;
    auto g2_mma = [&](int k) {
      const unsigned char* bufb = ring2 + (k & 1) * 5120;
      __builtin_amdgcn_s_setprio(1);
#pragma unroll
      for (int nt = 0; nt < 5; ++nt) {
        const int r = nt * 16 + l15;
        const half8 bb = *reinterpret_cast<const half8*>(
            bufb + r * 64 + ((koct ^ ((r >> 1) & 3)) << 4));
        acc2[nt][0] = MFMA16(p0, bb, acc2[nt][0]);
        acc2[nt][1] = MFMA16(p1, bb, acc2[nt][1]);
        acc2[nt][2] = MFMA16(p2, bb, acc2[nt][2]);
        acc2[nt][3] = MFMA16(p3, bb, acc2[nt][3]);
      }
      __builtin_amdgcn_s_setprio(0);
    };

    g2_stage(0);
    for (int k = 0; k < 15; ++k) {
      g2_stage(k + 1);
      p0 = *reinterpret_cast<const half8*>(&afrag[((k * 4 + 0) * 64 + lane) * 8]);
      p1 = *reinterpret_cast<const half8*>(&afrag[((k * 4 + 1) * 64 + lane) * 8]);
      p2 = *reinterpret_cast<const half8*>(&afrag[((k * 4 + 2) * 64 + lane) * 8]);
      p3 = *reinterpret_cast<const half8*>(&afrag[((k * 4 + 3) * 64 + lane) * 8]);
      VMW(5);  // own piece k complete (5 of k+1 outstanding)
      g2_mma(k);
    }
    p0 = *reinterpret_cast<const half8*>(&afrag[((15 * 4 + 0) * 64 + lane) * 8]);
    p1 = *reinterpret_cast<const half8*>(&afrag[((15 * 4 + 1) * 64 + lane) * 8]);
    p2 = *reinterpret_cast<const half8*>(&afrag[((15 * 4 + 2) * 64 + lane) * 8]);
    p3 = *reinterpret_cast<const half8*>(&afrag[((15 * 4 + 3) * 64 + lane) * 8]);
    VMW(0);
    g2_mma(15);
  }

  // ---- epilogue: nontemporal stores (skip pad tiles) ----
  {
    const int nbase = b * 4096 + h * 64;
#pragma unroll
    for (int nt = 0; nt < 5; ++nt) {
      const int dtile = wv * 5 + nt;
      if (dtile < 36) {
        const int d = dtile * 16 + l15;
#pragma unroll
        for (int pt = 0; pt < 4; ++pt)
#pragma unroll
          for (int r = 0; r < 4; ++r) {
            const int px = pt * 16 + koct * 4 + r;
            __builtin_nontemporal_store(acc2[nt][pt][r], &out[(nbase + px) * 576 + d]);
          }
      }
    }
  }
}

extern "C" void kernel_launch(void* const* d_in, const int* in_sizes, int n_in,
                              void* d_out, int out_size, void* d_ws, size_t ws_size,
                              hipStream_t stream) {
  const float* x = (const float*)d_in[0];
  const float* memory = (const float*)d_in[1];
  const float* temperature = (const float*)d_in[2];
  float* out = (float*)d_out;
  _Float16* ws = (_Float16*)d_ws;  // needs 1,769,472 bytes

  prep_split<<<512, 576, 0, stream>>>(memory, ws);
  mem_branch_kernel<<<1024, 512, 0, stream>>>(x, temperature, ws, out);
}